// Round 3
// baseline (32964.764 us; speedup 1.0000x reference)
//
#include <hip/hip_runtime.h>
#include <hip/hip_bf16.h>
#include <hip/hip_fp16.h>

#define S_LEN 8192
#define LC 16
#define CE 64
#define CH 64
#define WE 128
#define NTAGS 50

using bf16 = __hip_bfloat16;
typedef unsigned int u32;
typedef unsigned long long u64;

__device__ __forceinline__ float bfbits2f(unsigned short u) {
    union { unsigned int i; float f; } v; v.i = ((unsigned int)u) << 16; return v.f;
}
__device__ __forceinline__ float sigm(float x) {
    return __builtin_amdgcn_rcpf(1.0f + __expf(-x));
}
__device__ __forceinline__ float tanh_fast(float x) {
    return 1.0f - 2.0f * __builtin_amdgcn_rcpf(__expf(2.0f * x) + 1.0f);
}

// dtype-generic accessors ----------------------------------------------------
template <bool BF>
__device__ __forceinline__ float ld1(const void* p, size_t i) {
    if constexpr (BF) return bfbits2f(((const unsigned short*)p)[i]);
    else              return ((const float*)p)[i];
}
template <bool BF>
__device__ __forceinline__ float4 ld4(const void* p, size_t i) {  // elems i..i+3
    if constexpr (BF) {
        const ushort4 s = *reinterpret_cast<const ushort4*>((const unsigned short*)p + i);
        return make_float4(bfbits2f(s.x), bfbits2f(s.y), bfbits2f(s.z), bfbits2f(s.w));
    } else {
        return *reinterpret_cast<const float4*>((const float*)p + i);
    }
}
template <bool BF>
__device__ __forceinline__ void st1(void* p, size_t i, float v) {
    if constexpr (BF) ((bf16*)p)[i] = __float2bfloat16(v);
    else              ((float*)p)[i] = v;
}

// f16-pair helpers for the recurrent matvec (HW-validated R1/R2: absmax ok) --
typedef _Float16 h2t __attribute__((ext_vector_type(2)));

__device__ __forceinline__ u32 pk2(float a, float b) {        // RTE pack
    __half2 h = __floats2half2_rn(a, b);
    u32 r; __builtin_memcpy(&r, &h, 4); return r;
}
__device__ __forceinline__ float fdot2u(u32 a, u32 b, float c) {
#if __has_builtin(__builtin_amdgcn_fdot2)
    h2t av, bv;
    __builtin_memcpy(&av, &a, 4);
    __builtin_memcpy(&bv, &b, 4);
    return __builtin_amdgcn_fdot2(av, bv, c, false);
#else
    __half2 ah, bh;
    __builtin_memcpy(&ah, &a, 4);
    __builtin_memcpy(&bh, &b, 4);
    c = fmaf(__half2float(ah.x), __half2float(bh.x), c);
    c = fmaf(__half2float(ah.y), __half2float(bh.y), c);
    return c;
#endif
}

// LDS counter helpers (workgroup scope) -------------------------------------
__device__ __forceinline__ void lds_add_rel(u32* p) {
    __hip_atomic_fetch_add(p, 1u, __ATOMIC_RELEASE, __HIP_MEMORY_SCOPE_WORKGROUP);
}
__device__ __forceinline__ u32 lds_ld_acq(u32* p) {
    return __hip_atomic_load(p, __ATOMIC_ACQUIRE, __HIP_MEMORY_SCOPE_WORKGROUP);
}

// ---------------------------------------------------------------------------
// Detector: classify float-tensor dtype from char_emb's first 256 ushorts.
// Also bumps the workspace generation counter (election tag freshness).
// ---------------------------------------------------------------------------
__global__ void kdetect(const void* emb, u32* flag, u32* gen) {
    const int j = threadIdx.x;           // 64 lanes
    int s = 0;
    #pragma unroll
    for (int k = 0; k < 4; ++k) {
        const unsigned short u = ((const unsigned short*)emb)[j * 4 + k];
        const int e = (u >> 7) & 0xFF;
        s += (e >= 100 && e <= 133) ? 1 : 0;
    }
    #pragma unroll
    for (int off = 32; off >= 1; off >>= 1) s += __shfl_xor(s, off, 64);
    if (j == 0) { *flag = (s >= 200) ? 1u : 0u; *gen = *gen + 1u; }
}

// ---------------------------------------------------------------------------
// Kernel A: char LSTM. 8 words/block, 256 threads (thread j = gate row j).
// ---------------------------------------------------------------------------
template <bool BF>
__global__ __launch_bounds__(256, 2) void kchar(
        const u32* __restrict__ dtf,
        const int* __restrict__ char_idxs, const int* __restrict__ char_lens,
        const void* __restrict__ char_emb,
        const void* __restrict__ Wih, const void* __restrict__ Whh,
        const void* __restrict__ bih, const void* __restrict__ bhh,
        float* __restrict__ cfeat) {
    if ((*dtf != 0u) != BF) return;
    const int j = threadIdx.x;
    const int w0 = blockIdx.x * 8;

    __shared__ __align__(16) float emb_lds[128 * CE];     // 32 KB
    __shared__ __align__(16) float gates_lds[8 * 256];    // 8 KB
    __shared__ __align__(16) float h_lds[8 * CH];
    __shared__ __align__(16) float c_lds[8 * CH];
    __shared__ int cidx_lds[8 * LC];
    __shared__ int len_lds[8];

    {
        float4* emb4 = reinterpret_cast<float4*>(emb_lds);
        #pragma unroll
        for (int i = 0; i < 8; ++i) {
            const int c = i * 256 + j;
            emb4[c] = ld4<BF>(char_emb, (size_t)c * 4);
        }
    }
    if (j < 128) cidx_lds[j] = char_idxs[w0 * LC + j];
    if (j < 8)   len_lds[j]  = char_lens[w0 + j];
    h_lds[j] = 0.f; h_lds[j + 256] = 0.f;
    c_lds[j] = 0.f; c_lds[j + 256] = 0.f;

    float4 wih4[16], whh4[16];
    #pragma unroll
    for (int kc = 0; kc < 16; ++kc) {
        wih4[kc] = ld4<BF>(Wih, (size_t)j * CE + kc * 4);
        whh4[kc] = ld4<BF>(Whh, (size_t)j * CH + kc * 4);
    }
    const float bias = ld1<BF>(bih, j) + ld1<BF>(bhh, j);
    __syncthreads();

    for (int t = 0; t < LC; ++t) {
        for (int w = 0; w < 8; ++w) {
            const int ci = cidx_lds[w * LC + t];
            const float4* x4  = reinterpret_cast<const float4*>(emb_lds + ci * CE);
            const float4* hh4 = reinterpret_cast<const float4*>(h_lds + w * CH);
            float a0 = 0.f, a1 = 0.f, a2 = 0.f, a3 = 0.f;
            #pragma unroll
            for (int kc = 0; kc < 16; ++kc) {
                const float4 xv = x4[kc]; const float4 hv = hh4[kc];
                const float4 wi = wih4[kc]; const float4 wh = whh4[kc];
                a0 = fmaf(wi.x, xv.x, a0); a1 = fmaf(wi.y, xv.y, a1);
                a2 = fmaf(wi.z, xv.z, a2); a3 = fmaf(wi.w, xv.w, a3);
                a0 = fmaf(wh.x, hv.x, a0); a1 = fmaf(wh.y, hv.y, a1);
                a2 = fmaf(wh.z, hv.z, a2); a3 = fmaf(wh.w, hv.w, a3);
            }
            gates_lds[w * 256 + j] = bias + ((a0 + a1) + (a2 + a3));
        }
        __syncthreads();
        #pragma unroll
        for (int rep = 0; rep < 2; ++rep) {
            const int p = j + rep * 256;       // p = w*64 + u
            const int w = p >> 6, u = p & 63;
            const float ig = gates_lds[w * 256 + u];
            const float fg = gates_lds[w * 256 + 64 + u];
            const float gg = gates_lds[w * 256 + 128 + u];
            const float og = gates_lds[w * 256 + 192 + u];
            const float cn = sigm(fg) * c_lds[p] + sigm(ig) * tanh_fast(gg);
            const float hn = sigm(og) * tanh_fast(cn);
            c_lds[p] = cn; h_lds[p] = hn;
            if (t == len_lds[w] - 1)
                cfeat[(size_t)(w0 + w) * CH + u] = hn;
        }
        __syncthreads();
    }
}

// ---------------------------------------------------------------------------
// Kernel B: Gx ring chunk. 16 words/block.
// ---------------------------------------------------------------------------
template <bool BF>
__global__ __launch_bounds__(256) void kgx(
        const u32* __restrict__ dtf,
        int t0, const int* __restrict__ word_idxs, const float* __restrict__ cfeat,
        const void* __restrict__ wemb, const void* __restrict__ Wih,
        const void* __restrict__ bih, const void* __restrict__ bhh,
        float* __restrict__ Gxr) {
    if ((*dtf != 0u) != BF) return;
    const int j = threadIdx.x;
    const int wr0 = blockIdx.x * 16;       // ring row base
    const int w0g = t0 + wr0;              // global word base
    __shared__ __align__(16) float wx[16 * 192];
    __shared__ int widx[16];
    if (j < 16) widx[j] = word_idxs[w0g + j];
    __syncthreads();
    {
        const int w = j >> 4, ch = j & 15;
        const size_t eb = (size_t)widx[w] * WE + ch * 8;
        const float4 f0 = ld4<BF>(wemb, eb), f1 = ld4<BF>(wemb, eb + 4);
        float4* dst = reinterpret_cast<float4*>(wx + w * 192 + ch * 8);
        dst[0] = f0; dst[1] = f1;
        const float4 cf = *reinterpret_cast<const float4*>(
            cfeat + (size_t)(w0g + w) * CH + ch * 4);
        *reinterpret_cast<float4*>(wx + w * 192 + WE + ch * 4) = cf;
    }
    __syncthreads();

    for (int g = 0; g < 4; ++g) {
        const int r = g * 256 + j;
        float acc[16];
        #pragma unroll
        for (int w = 0; w < 16; ++w) acc[w] = 0.f;
        #pragma unroll 8
        for (int kc = 0; kc < 48; ++kc) {
            const float4 wv = ld4<BF>(Wih, (size_t)r * 192 + kc * 4);
            #pragma unroll
            for (int w = 0; w < 16; ++w) {
                const float4 xv = *reinterpret_cast<const float4*>(wx + w * 192 + kc * 4);
                acc[w] = fmaf(wv.x, xv.x, acc[w]);
                acc[w] = fmaf(wv.y, xv.y, acc[w]);
                acc[w] = fmaf(wv.z, xv.z, acc[w]);
                acc[w] = fmaf(wv.w, xv.w, acc[w]);
            }
        }
        const float bias = ld1<BF>(bih, r) + ld1<BF>(bhh, r);
        #pragma unroll
        for (int w = 0; w < 16; ++w)
            Gxr[(size_t)(wr0 + w) * 1024 + r] = acc[w] + bias;
    }
}

// ---------------------------------------------------------------------------
// Kernel C: word LSTM steps [t0, t1). Grid = 64 x 512; election picks 4
// worker blocks (same-XCD preferred). Agent-scope u64 tagged packets —
// byte-identical protocol to the R2-verified version.
//
// R3 change: remove the per-step barrier; compute waves consume h
// QUARTER-BY-QUARTER as packets arrive, synchronized by cumulative LDS
// counters (release/acquire). R2 evidence: two totally different compute
// layouts both landed at 3160cy/step -> critical path is publish->observe
// RT + detect jitter; the serialized full matvec after the barrier was
// ~500-700cy of avoidable tail. Now after the LAST-arriving quarter only
// ~8 LDS reads + 32 dot2 + gates remain.
//
//  waves 0-3 = compute (lane owns full Whh row, 128 f16-pair dwords)
//  waves 4-6 = poll 192 remote packets; wave 7 exits after init
//  qcnt[2][4]: cumulative dword-writer counts per (parity, worker-quarter);
//              32 writers/quarter/step. Compute spins to a cumulative target
//              (+32/step/parity). No resets -> no reset races.
//  wdone[4]:   cumulative steps consumed per compute wave. Pollers (and hn
//              publishers) gate h2[p] WRITES on consumers being done with
//              step t-2 (same parity) -> overrun-safe without barriers.
//              Never engages in steady state (compute runs ahead of RT).
// ---------------------------------------------------------------------------
template <bool BF>
__global__ __launch_bounds__(512, 2) void kwlstm(
        const u32* __restrict__ dtf,
        int t0, int t1, int epoch, const void* __restrict__ whh,
        const float* __restrict__ Gxr,
        float* __restrict__ hallr, u64* hgx2, float* csave, u32* xccpub,
        const u32* __restrict__ genp) {
    if ((*dtf != 0u) != BF) return;
    const int j = threadIdx.x;

    __shared__ int role_s;
    // ---- same-XCD election (generation+epoch-tagged, agent scope) ----
    const u32 et = (((*genp) << 8) + (u32)epoch) & 0xFFFFFFu;
    if (j == 0) {
        const u32 xcc = __builtin_amdgcn_s_getreg(6164) & 0xFu;  // hwreg(XCC_ID,0,4)
        __hip_atomic_store(&xccpub[blockIdx.x], (et << 8) | xcc,
                           __ATOMIC_RELAXED, __HIP_MEMORY_SCOPE_AGENT);
    }
    if (j < 64) {
        u32 v;
        do {
            v = __hip_atomic_load(&xccpub[j], __ATOMIC_RELAXED,
                                  __HIP_MEMORY_SCOPE_AGENT);
        } while ((v >> 8) != et);
        const u32 v0 = __shfl(v, 0, 64);
        const u64 mask = __ballot((v & 0xFFu) == (v0 & 0xFFu));
        const int myb = blockIdx.x;
        int role = -1;
        if (__popcll(mask) >= 4) {
            if ((mask >> myb) & 1ull) {
                const int rank = __popcll(mask & ((1ull << myb) - 1ull));
                if (rank < 4) role = rank;
            }
        } else {
            if (myb < 4) role = myb;   // fallback: cross-XCD, still correct
        }
        if (j == 0) role_s = role;
    }
    __syncthreads();
    const int b = role_s;
    if (b < 0) return;

    const int wv_id   = j >> 6;            // wave 0..7
    const bool is_comp = (wv_id < 4);
    const int l = j & 63;
    const int m = l & 15;                  // unit-in-group
    const int g = l >> 4;                  // gate 0..3 (i,f,g,o)
    const int u = wv_id * 16 + m;          // unit within worker (compute waves)
    const int R = g * 256 + b * 64 + u;    // global gate row
    const int pj = j - 256;                // poll index (waves 4-7): 0..255

    __shared__ __align__(16) u32 h2[2][128];   // f16-pair h, parity-buffered
    __shared__ u32 qcnt[2][4];                 // cumulative writer counts
    __shared__ u32 wdone[4];                   // cumulative consumed steps

    // Whh full row as 128 f16-pair dwords, resident in VGPRs (compute waves).
    u32 wv2[128];
    if (is_comp) {
        #pragma unroll
        for (int kc = 0; kc < 64; ++kc) {
            const float4 w = ld4<BF>(whh, (size_t)R * 256 + kc * 4);
            wv2[2 * kc]     = pk2(w.x, w.y);
            wv2[2 * kc + 1] = pk2(w.z, w.w);
        }
    }
    if (j < 128) { h2[0][j] = 0u; h2[1][j] = 0u; }
    if (j < 8)   qcnt[j >> 2][j & 3] = 0u;
    if (j < 4)   wdone[j] = 0u;

    const bool is_hn = is_comp && (l < 16);
    float c_reg = 0.f;
    if (t0 > 0 && is_hn) c_reg = csave[b * 64 + u];

    // 2-deep Gx pipeline (compute lanes; row R of ring)
    float gxA = 0.f, gxB = 0.f;
    if (is_comp) {
        gxA = Gxr[(size_t)0 * 1024 + R];
        if (t0 + 1 < t1) gxB = Gxr[(size_t)1 * 1024 + R];
    }
    __syncthreads();   // zero-init of h2/qcnt/wdone visible

    if (!is_comp && pj >= 192) return;   // wave 7: idle, no barriers follow

    // chunk start (t0>0): hn lanes gather OWN h(t0) (self-published last
    // chunk) and count it; pollers fetch the 192 remote in loop iter t0.
    if (t0 > 0 && is_hn) {
        u64 pk;
        do {
            pk = __hip_atomic_load(&hgx2[(size_t)(t0 & 1) * 256 + b * 64 + u],
                                   __ATOMIC_RELAXED, __HIP_MEMORY_SCOPE_AGENT);
        } while ((u32)(pk >> 32) != (u32)t0);
        const float hv = __uint_as_float((u32)pk);
        const float ho = __shfl_xor(hv, 1, 64);
        if (!(m & 1)) {
            h2[t0 & 1][(b * 64 + u) >> 1] = pk2(hv, ho);
            lds_add_rel(&qcnt[t0 & 1][b]);
        }
    }

    // cumulative consume-targets for current/other parity (swap each step).
    // t0==0: step0 reads the zero-filled buffer (target 0 -> no spin).
    u32 tgtP = (t0 == 0) ? 0u : 32u;
    u32 tgtQ = 32u;

    for (int t = t0; t < t1; ++t) {
        const int p = t & 1;
        const int n = t - t0;

        if (!is_comp) {
            // ---- poll waves 4-6: fetch the 192 remote h(t) ----
            if (t > 0) {
                const int gu = pj + (pj >= b * 64 ? 64 : 0);
                u64 pk;
                do {
                    pk = __hip_atomic_load(&hgx2[(size_t)p * 256 + gu],
                                           __ATOMIC_RELAXED, __HIP_MEMORY_SCOPE_AGENT);
                } while ((u32)(pk >> 32) != (u32)t);
                const float hv = __uint_as_float((u32)pk);
                const float ho = __shfl_xor(hv, 1, 64);
                if (n >= 2) {               // overrun guard vs readers of t-2
                    u32 mn;
                    do {
                        mn = lds_ld_acq(&wdone[0]);
                        mn = min(mn, lds_ld_acq(&wdone[1]));
                        mn = min(mn, lds_ld_acq(&wdone[2]));
                        mn = min(mn, lds_ld_acq(&wdone[3]));
                    } while (mn < (u32)(n - 1));
                }
                if (!(pj & 1)) {
                    h2[p][gu >> 1] = pk2(hv, ho);
                    lds_add_rel(&qcnt[p][gu >> 6]);
                }
            }
        } else {
            // ---- compute waves 0-3 ----
            float gxN = 0.f;                           // prefetch Gx[t+2]
            if (t + 2 < t1) gxN = Gxr[(size_t)(t + 2 - t0) * 1024 + R];

            float a0 = 0.f, a1 = 0.f, a2 = 0.f, a3 = 0.f;
            u32* qc = &qcnt[p][0];
            #pragma unroll
            for (int q = 0; q < 4; ++q) {              // compile-time q (no
                if (tgtP > 0) {                        //  runtime wv2 index!)
                    u32 v;
                    do { v = lds_ld_acq(qc + q); } while (v < tgtP);
                }
                const uint4* h4q = reinterpret_cast<const uint4*>(&h2[p][q * 32]);
                #pragma unroll
                for (int kc = 0; kc < 8; ++kc) {
                    const uint4 hv = h4q[kc];          // wave-uniform broadcast
                    a0 = fdot2u(wv2[q * 32 + 4 * kc + 0], hv.x, a0);
                    a1 = fdot2u(wv2[q * 32 + 4 * kc + 1], hv.y, a1);
                    a2 = fdot2u(wv2[q * 32 + 4 * kc + 2], hv.z, a2);
                    a3 = fdot2u(wv2[q * 32 + 4 * kc + 3], hv.w, a3);
                }
            }
            tgtP += 32u;
            if (l == 0) lds_add_rel(&wdone[wv_id]);    // release drains ds_reads

            const float gv = ((a0 + a1) + (a2 + a3)) + gxA;
            // activation: gate g==2 (cell candidate) uses tanh, others sigmoid
            const float act = (g == 2) ? tanh_fast(gv) : sigm(gv);
            const float a_f = __shfl(act, m + 16, 64);
            const float a_g = __shfl(act, m + 32, 64);
            const float a_o = __shfl(act, m + 48, 64);
            if (l < 16) {                              // act == sigm(i) here
                const float cn = a_f * c_reg + act * a_g;
                c_reg = cn;
                const float hn = a_o * tanh_fast(cn);
                if (n >= 1) {               // overrun guard vs readers of t-1
                    u32 mn;
                    do {
                        mn = lds_ld_acq(&wdone[0]);
                        mn = min(mn, lds_ld_acq(&wdone[1]));
                        mn = min(mn, lds_ld_acq(&wdone[2]));
                        mn = min(mn, lds_ld_acq(&wdone[3]));
                    } while (mn < (u32)n);
                }
                // publish FIRST (remote critical path)
                const u64 pk = ((u64)(u32)(t + 1) << 32) | (u64)__float_as_uint(hn);
                __hip_atomic_store(&hgx2[(size_t)((t + 1) & 1) * 256 + b * 64 + u],
                                   pk, __ATOMIC_RELAXED, __HIP_MEMORY_SCOPE_AGENT);
                const float ho = __shfl_xor(hn, 1, 64);
                if (!(m & 1)) {
                    h2[(t + 1) & 1][(b * 64 + u) >> 1] = pk2(hn, ho);
                    lds_add_rel(&qcnt[(t + 1) & 1][b]);
                }
                hallr[(size_t)(t - t0) * 256 + b * 64 + u] = hn;
            }
            gxA = gxB; gxB = gxN;
        }
        { const u32 tmp = tgtP; tgtP = tgtQ; tgtQ = tmp; }
    }
    if (is_hn) csave[b * 64 + u] = c_reg;
}

// ---------------------------------------------------------------------------
// Kernel D: logits + log_softmax. One wave per word.
// ---------------------------------------------------------------------------
template <bool BF>
__global__ __launch_bounds__(64) void ktag(
        const u32* __restrict__ dtf,
        int t0, const float* __restrict__ hallr, const void* __restrict__ tagW,
        const void* __restrict__ tagb, void* __restrict__ out) {
    if ((*dtf != 0u) != BF) return;
    const int tr = blockIdx.x, j = threadIdx.x;
    const int t = t0 + tr;
    __shared__ __align__(16) float4 h4[64];
    h4[j] = reinterpret_cast<const float4*>(hallr + (size_t)tr * 256)[j];
    __syncthreads();
    float logit = -1e30f;
    if (j < NTAGS) {
        float a0 = 0.f, a1 = 0.f, a2 = 0.f, a3 = 0.f;
        #pragma unroll
        for (int kc = 0; kc < 64; ++kc) {
            const float4 wvv = ld4<BF>(tagW, (size_t)j * 256 + kc * 4);
            const float4 hv = h4[kc];
            a0 = fmaf(wvv.x, hv.x, a0); a1 = fmaf(wvv.y, hv.y, a1);
            a2 = fmaf(wvv.z, hv.z, a2); a3 = fmaf(wvv.w, hv.w, a3);
        }
        logit = ld1<BF>(tagb, j) + ((a0 + a1) + (a2 + a3));
    }
    float m = logit;
    #pragma unroll
    for (int off = 32; off >= 1; off >>= 1) m = fmaxf(m, __shfl_xor(m, off, 64));
    const float e = (j < NTAGS) ? __expf(logit - m) : 0.f;
    float ssum = e;
    #pragma unroll
    for (int off = 32; off >= 1; off >>= 1) ssum += __shfl_xor(ssum, off, 64);
    if (j < NTAGS)
        st1<BF>(out, (size_t)t * NTAGS + j, logit - m - __logf(ssum));
}

// ---------------------------------------------------------------------------
extern "C" void kernel_launch(void* const* d_in, const int* in_sizes, int n_in,
                              void* d_out, int out_size, void* d_ws, size_t ws_size,
                              hipStream_t stream) {
    const int*  word_idxs = (const int*)d_in[0];
    const int*  char_idxs = (const int*)d_in[1];
    const int*  char_lens = (const int*)d_in[2];
    const void* char_emb  = d_in[3];
    const void* char_Wih  = d_in[4];
    const void* char_Whh  = d_in[5];
    const void* char_bih  = d_in[6];
    const void* char_bhh  = d_in[7];
    const void* word_emb  = d_in[8];
    const void* word_Wih  = d_in[9];
    const void* word_Whh  = d_in[10];
    const void* word_bih  = d_in[11];
    const void* word_bhh  = d_in[12];
    const void* tag_W     = d_in[13];
    const void* tag_b     = d_in[14];

    // ws layout:
    //   [0,64)        dtflag u32
    //   [64,4160)     hgx2 u64[2][256]
    //   [4224,5248)   csave f32[256]
    //   [5248,5504)   xccpub u32[64]
    //   [5504,5508)   gen u32 (persists across launches)
    //   [8192,+2MB)   cfeat f32[8192*64]
    //   [ring0,...)   Gx ring f32[CT*1024] + hall ring f32[CT*256]
    char* ws = (char*)d_ws;
    u32*   dtf    = (u32*)(ws);
    u64*   hgx2   = (u64*)(ws + 64);
    float* csave  = (float*)(ws + 4224);
    u32*   xccpub = (u32*)(ws + 5248);
    u32*   genp   = (u32*)(ws + 5504);
    float* cfeat  = (float*)(ws + 8192);
    const size_t ring0 = 8192 + (size_t)S_LEN * CH * 4;

    int NC = 256;
    const int ncs[9] = {1, 2, 4, 8, 16, 32, 64, 128, 256};
    for (int i = 0; i < 9; ++i) {
        const int ct = S_LEN / ncs[i];
        if (ring0 + (size_t)ct * 5120 <= ws_size) { NC = ncs[i]; break; }
    }
    const int CT = S_LEN / NC;
    float* Gxr   = (float*)(ws + ring0);
    float* hallr = (float*)(ws + ring0 + (size_t)CT * 4096);

    hipLaunchKernelGGL(kdetect, dim3(1), dim3(64), 0, stream, char_emb, dtf, genp);
    hipLaunchKernelGGL(kchar<true>,  dim3(S_LEN / 8), dim3(256), 0, stream,
                       dtf, char_idxs, char_lens, char_emb, char_Wih, char_Whh,
                       char_bih, char_bhh, cfeat);
    hipLaunchKernelGGL(kchar<false>, dim3(S_LEN / 8), dim3(256), 0, stream,
                       dtf, char_idxs, char_lens, char_emb, char_Wih, char_Whh,
                       char_bih, char_bhh, cfeat);
    for (int c = 0; c < NC; ++c) {
        const int t0 = c * CT;
        hipLaunchKernelGGL(kgx<true>,  dim3(CT / 16), dim3(256), 0, stream,
                           dtf, t0, word_idxs, cfeat, word_emb, word_Wih,
                           word_bih, word_bhh, Gxr);
        hipLaunchKernelGGL(kgx<false>, dim3(CT / 16), dim3(256), 0, stream,
                           dtf, t0, word_idxs, cfeat, word_emb, word_Wih,
                           word_bih, word_bhh, Gxr);
        hipLaunchKernelGGL(kwlstm<true>,  dim3(64), dim3(512), 0, stream,
                           dtf, t0, t0 + CT, c, word_Whh, Gxr, hallr, hgx2,
                           csave, xccpub, genp);
        hipLaunchKernelGGL(kwlstm<false>, dim3(64), dim3(512), 0, stream,
                           dtf, t0, t0 + CT, c, word_Whh, Gxr, hallr, hgx2,
                           csave, xccpub, genp);
        hipLaunchKernelGGL(ktag<true>,  dim3(CT), dim3(64), 0, stream,
                           dtf, t0, hallr, tag_W, tag_b, d_out);
        hipLaunchKernelGGL(ktag<false>, dim3(CT), dim3(64), 0, stream,
                           dtf, t0, hallr, tag_W, tag_b, d_out);
    }
}

// Round 5
// 14605.824 us; speedup vs baseline: 2.2570x; 2.2570x over previous
//
#include <hip/hip_runtime.h>
#include <hip/hip_bf16.h>
#include <hip/hip_fp16.h>

#define S_LEN 8192
#define LC 16
#define CE 64
#define CH 64
#define WE 128
#define NTAGS 50

using bf16 = __hip_bfloat16;
typedef unsigned int u32;
typedef unsigned long long u64;

__device__ __forceinline__ float bfbits2f(unsigned short u) {
    union { unsigned int i; float f; } v; v.i = ((unsigned int)u) << 16; return v.f;
}
__device__ __forceinline__ float sigm(float x) {
    return __builtin_amdgcn_rcpf(1.0f + __expf(-x));
}
__device__ __forceinline__ float tanh_fast(float x) {
    return 1.0f - 2.0f * __builtin_amdgcn_rcpf(__expf(2.0f * x) + 1.0f);
}

// dtype-generic accessors ----------------------------------------------------
template <bool BF>
__device__ __forceinline__ float ld1(const void* p, size_t i) {
    if constexpr (BF) return bfbits2f(((const unsigned short*)p)[i]);
    else              return ((const float*)p)[i];
}
template <bool BF>
__device__ __forceinline__ float4 ld4(const void* p, size_t i) {  // elems i..i+3
    if constexpr (BF) {
        const ushort4 s = *reinterpret_cast<const ushort4*>((const unsigned short*)p + i);
        return make_float4(bfbits2f(s.x), bfbits2f(s.y), bfbits2f(s.z), bfbits2f(s.w));
    } else {
        return *reinterpret_cast<const float4*>((const float*)p + i);
    }
}
template <bool BF>
__device__ __forceinline__ void st1(void* p, size_t i, float v) {
    if constexpr (BF) ((bf16*)p)[i] = __float2bfloat16(v);
    else              ((float*)p)[i] = v;
}

// f16-pair helpers for the recurrent matvec (HW-validated R1/R2: absmax ok) --
typedef _Float16 h2t __attribute__((ext_vector_type(2)));

__device__ __forceinline__ u32 pk2(float a, float b) {        // RTE pack
    __half2 h = __floats2half2_rn(a, b);
    u32 r; __builtin_memcpy(&r, &h, 4); return r;
}
__device__ __forceinline__ float fdot2u(u32 a, u32 b, float c) {
#if __has_builtin(__builtin_amdgcn_fdot2)
    h2t av, bv;
    __builtin_memcpy(&av, &a, 4);
    __builtin_memcpy(&bv, &b, 4);
    return __builtin_amdgcn_fdot2(av, bv, c, false);
#else
    __half2 ah, bh;
    __builtin_memcpy(&ah, &a, 4);
    __builtin_memcpy(&bh, &b, 4);
    c = fmaf(__half2float(ah.x), __half2float(bh.x), c);
    c = fmaf(__half2float(ah.y), __half2float(bh.y), c);
    return c;
#endif
}

// ---------------------------------------------------------------------------
// Detector: classify float-tensor dtype from char_emb's first 256 ushorts.
// Also bumps the workspace generation counter (election tag freshness).
// ---------------------------------------------------------------------------
__global__ void kdetect(const void* emb, u32* flag, u32* gen) {
    const int j = threadIdx.x;           // 64 lanes
    int s = 0;
    #pragma unroll
    for (int k = 0; k < 4; ++k) {
        const unsigned short u = ((const unsigned short*)emb)[j * 4 + k];
        const int e = (u >> 7) & 0xFF;
        s += (e >= 100 && e <= 133) ? 1 : 0;
    }
    #pragma unroll
    for (int off = 32; off >= 1; off >>= 1) s += __shfl_xor(s, off, 64);
    if (j == 0) { *flag = (s >= 200) ? 1u : 0u; *gen = *gen + 1u; }
}

// ---------------------------------------------------------------------------
// Kernel A: char LSTM. 8 words/block, 256 threads (thread j = gate row j).
// ---------------------------------------------------------------------------
template <bool BF>
__global__ __launch_bounds__(256, 2) void kchar(
        const u32* __restrict__ dtf,
        const int* __restrict__ char_idxs, const int* __restrict__ char_lens,
        const void* __restrict__ char_emb,
        const void* __restrict__ Wih, const void* __restrict__ Whh,
        const void* __restrict__ bih, const void* __restrict__ bhh,
        float* __restrict__ cfeat) {
    if ((*dtf != 0u) != BF) return;
    const int j = threadIdx.x;
    const int w0 = blockIdx.x * 8;

    __shared__ __align__(16) float emb_lds[128 * CE];     // 32 KB
    __shared__ __align__(16) float gates_lds[8 * 256];    // 8 KB
    __shared__ __align__(16) float h_lds[8 * CH];
    __shared__ __align__(16) float c_lds[8 * CH];
    __shared__ int cidx_lds[8 * LC];
    __shared__ int len_lds[8];

    {
        float4* emb4 = reinterpret_cast<float4*>(emb_lds);
        #pragma unroll
        for (int i = 0; i < 8; ++i) {
            const int c = i * 256 + j;
            emb4[c] = ld4<BF>(char_emb, (size_t)c * 4);
        }
    }
    if (j < 128) cidx_lds[j] = char_idxs[w0 * LC + j];
    if (j < 8)   len_lds[j]  = char_lens[w0 + j];
    h_lds[j] = 0.f; h_lds[j + 256] = 0.f;
    c_lds[j] = 0.f; c_lds[j + 256] = 0.f;

    float4 wih4[16], whh4[16];
    #pragma unroll
    for (int kc = 0; kc < 16; ++kc) {
        wih4[kc] = ld4<BF>(Wih, (size_t)j * CE + kc * 4);
        whh4[kc] = ld4<BF>(Whh, (size_t)j * CH + kc * 4);
    }
    const float bias = ld1<BF>(bih, j) + ld1<BF>(bhh, j);
    __syncthreads();

    for (int t = 0; t < LC; ++t) {
        for (int w = 0; w < 8; ++w) {
            const int ci = cidx_lds[w * LC + t];
            const float4* x4  = reinterpret_cast<const float4*>(emb_lds + ci * CE);
            const float4* hh4 = reinterpret_cast<const float4*>(h_lds + w * CH);
            float a0 = 0.f, a1 = 0.f, a2 = 0.f, a3 = 0.f;
            #pragma unroll
            for (int kc = 0; kc < 16; ++kc) {
                const float4 xv = x4[kc]; const float4 hv = hh4[kc];
                const float4 wi = wih4[kc]; const float4 wh = whh4[kc];
                a0 = fmaf(wi.x, xv.x, a0); a1 = fmaf(wi.y, xv.y, a1);
                a2 = fmaf(wi.z, xv.z, a2); a3 = fmaf(wi.w, xv.w, a3);
                a0 = fmaf(wh.x, hv.x, a0); a1 = fmaf(wh.y, hv.y, a1);
                a2 = fmaf(wh.z, hv.z, a2); a3 = fmaf(wh.w, hv.w, a3);
            }
            gates_lds[w * 256 + j] = bias + ((a0 + a1) + (a2 + a3));
        }
        __syncthreads();
        #pragma unroll
        for (int rep = 0; rep < 2; ++rep) {
            const int p = j + rep * 256;       // p = w*64 + u
            const int w = p >> 6, u = p & 63;
            const float ig = gates_lds[w * 256 + u];
            const float fg = gates_lds[w * 256 + 64 + u];
            const float gg = gates_lds[w * 256 + 128 + u];
            const float og = gates_lds[w * 256 + 192 + u];
            const float cn = sigm(fg) * c_lds[p] + sigm(ig) * tanh_fast(gg);
            const float hn = sigm(og) * tanh_fast(cn);
            c_lds[p] = cn; h_lds[p] = hn;
            if (t == len_lds[w] - 1)
                cfeat[(size_t)(w0 + w) * CH + u] = hn;
        }
        __syncthreads();
    }
}

// ---------------------------------------------------------------------------
// Kernel B: Gx ring chunk. 16 words/block.
// ---------------------------------------------------------------------------
template <bool BF>
__global__ __launch_bounds__(256) void kgx(
        const u32* __restrict__ dtf,
        int t0, const int* __restrict__ word_idxs, const float* __restrict__ cfeat,
        const void* __restrict__ wemb, const void* __restrict__ Wih,
        const void* __restrict__ bih, const void* __restrict__ bhh,
        float* __restrict__ Gxr) {
    if ((*dtf != 0u) != BF) return;
    const int j = threadIdx.x;
    const int wr0 = blockIdx.x * 16;       // ring row base
    const int w0g = t0 + wr0;              // global word base
    __shared__ __align__(16) float wx[16 * 192];
    __shared__ int widx[16];
    if (j < 16) widx[j] = word_idxs[w0g + j];
    __syncthreads();
    {
        const int w = j >> 4, ch = j & 15;
        const size_t eb = (size_t)widx[w] * WE + ch * 8;
        const float4 f0 = ld4<BF>(wemb, eb), f1 = ld4<BF>(wemb, eb + 4);
        float4* dst = reinterpret_cast<float4*>(wx + w * 192 + ch * 8);
        dst[0] = f0; dst[1] = f1;
        const float4 cf = *reinterpret_cast<const float4*>(
            cfeat + (size_t)(w0g + w) * CH + ch * 4);
        *reinterpret_cast<float4*>(wx + w * 192 + WE + ch * 4) = cf;
    }
    __syncthreads();

    for (int g = 0; g < 4; ++g) {
        const int r = g * 256 + j;
        float acc[16];
        #pragma unroll
        for (int w = 0; w < 16; ++w) acc[w] = 0.f;
        #pragma unroll 8
        for (int kc = 0; kc < 48; ++kc) {
            const float4 wv = ld4<BF>(Wih, (size_t)r * 192 + kc * 4);
            #pragma unroll
            for (int w = 0; w < 16; ++w) {
                const float4 xv = *reinterpret_cast<const float4*>(wx + w * 192 + kc * 4);
                acc[w] = fmaf(wv.x, xv.x, acc[w]);
                acc[w] = fmaf(wv.y, xv.y, acc[w]);
                acc[w] = fmaf(wv.z, xv.z, acc[w]);
                acc[w] = fmaf(wv.w, xv.w, acc[w]);
            }
        }
        const float bias = ld1<BF>(bih, r) + ld1<BF>(bhh, r);
        #pragma unroll
        for (int w = 0; w < 16; ++w)
            Gxr[(size_t)(wr0 + w) * 1024 + r] = acc[w] + bias;
    }
}

// ---------------------------------------------------------------------------
// Kernel C: word LSTM steps [t0, t1). Grid = 64 x 256; election picks 4
// worker blocks (same-XCD preferred). Agent-scope u64 tagged packets
// (byte-identical protocol to the R2-proven version).
//
// R4 structure (zero shared synchronization in the step loop) + R5 fix:
//  * R4 FAILED (absmax 0.41) due to a TBAA miscompile: hsc was WRITTEN as
//    u32 but READ as uint4 via reinterpret_cast with NO barrier between.
//    Clang's alias analysis may treat u32 stores and uint4 loads as
//    non-aliasing -> reads hoisted/cached across the write -> stale h in
//    the dots. (R2 had the same pun on h2 but __syncthreads() between
//    write and read acted as a memory clobber -> hidden.)
//  * R5 FIX: hsc is read through the SAME type (u32 element loads; the
//    compiler merges adjacent LDS loads into ds_read_b128 with correct
//    aliasing), plus zero-cost asm memory clobbers after the write and
//    after the reads to forbid any residual motion. HW DS ops are
//    processed in-order per wave, so no extra waitcnt is needed.
//  * Everything else identical to R4: 4 waves; wave w owns 16 units x 4
//    gates, full Whh rows in 128 f16-pair VGPRs (poll-ordered, indices
//    compile-time); each wave polls the 4 h-quarters directly from global
//    (64-lane coalesced atomic load + __all tag vote), own quarter first;
//    gate math in-wave via 3 shuffles; lanes l<16 publish h(t+1).
//  Safety: a worker publishes t+1 only after consuming all quarters of t
//  (implies all workers finished parity t-1 -> overwrite-safe). Stale
//  cross-run tags can only exact-match with identical (deterministic)
//  values -> benign. t==0 skips polling (h=0).
// ---------------------------------------------------------------------------
template <bool BF>
__global__ __launch_bounds__(256, 1) void kwlstm(
        const u32* __restrict__ dtf,
        int t0, int t1, int epoch, const void* __restrict__ whh,
        const float* __restrict__ Gxr,
        float* __restrict__ hallr, u64* hgx2, float* csave, u32* xccpub,
        const u32* __restrict__ genp) {
    if ((*dtf != 0u) != BF) return;
    const int j = threadIdx.x;

    __shared__ int role_s;
    // ---- same-XCD election (generation+epoch-tagged, agent scope) ----
    const u32 et = (((*genp) << 8) + (u32)epoch) & 0xFFFFFFu;
    if (j == 0) {
        const u32 xcc = __builtin_amdgcn_s_getreg(6164) & 0xFu;  // hwreg(XCC_ID,0,4)
        __hip_atomic_store(&xccpub[blockIdx.x], (et << 8) | xcc,
                           __ATOMIC_RELAXED, __HIP_MEMORY_SCOPE_AGENT);
    }
    if (j < 64) {
        u32 v;
        do {
            v = __hip_atomic_load(&xccpub[j], __ATOMIC_RELAXED,
                                  __HIP_MEMORY_SCOPE_AGENT);
        } while ((v >> 8) != et);
        const u32 v0 = __shfl(v, 0, 64);
        const u64 mask = __ballot((v & 0xFFu) == (v0 & 0xFFu));
        const int myb = blockIdx.x;
        int role = -1;
        if (__popcll(mask) >= 4) {
            if ((mask >> myb) & 1ull) {
                const int rank = __popcll(mask & ((1ull << myb) - 1ull));
                if (rank < 4) role = rank;
            }
        } else {
            if (myb < 4) role = myb;   // fallback: cross-XCD, still correct
        }
        if (j == 0) role_s = role;
    }
    __syncthreads();
    const int b = role_s;
    if (b < 0) return;

    const int w = j >> 6;              // wave 0..3
    const int l = j & 63;
    const int m = l & 15;              // unit-in-group
    const int g = l >> 4;              // gate 0..3 (i,f,g,o)
    const int u = w * 16 + m;          // unit within worker
    const int R = g * 256 + b * 64 + u;  // global gate row

    __shared__ __align__(16) u32 hsc[4][32];   // per-wave f16-pair scratch

    // Whh full row, 128 f16-pair dwords, in POLL order: reg-slot q covers
    // h-quarter (b+q)&3 (own first). Register indices stay compile-time.
    u32 wv2[128];
    #pragma unroll
    for (int q = 0; q < 4; ++q) {
        const int qq = (b + q) & 3;
        #pragma unroll
        for (int kc = 0; kc < 8; ++kc) {
            const float4 wa = ld4<BF>(whh, (size_t)R * 256 + qq * 64 + kc * 8);
            const float4 wb = ld4<BF>(whh, (size_t)R * 256 + qq * 64 + kc * 8 + 4);
            wv2[q * 32 + 4 * kc + 0] = pk2(wa.x, wa.y);
            wv2[q * 32 + 4 * kc + 1] = pk2(wa.z, wa.w);
            wv2[q * 32 + 4 * kc + 2] = pk2(wb.x, wb.y);
            wv2[q * 32 + 4 * kc + 3] = pk2(wb.z, wb.w);
        }
    }

    float c_reg = 0.f;
    if (t0 > 0 && l < 16) c_reg = csave[b * 64 + u];

    // 2-deep Gx pipeline (row R of ring)
    float gxA = Gxr[(size_t)0 * 1024 + R];
    float gxB = (t0 + 1 < t1) ? Gxr[(size_t)1 * 1024 + R] : 0.f;

    for (int t = t0; t < t1; ++t) {
        const int p = t & 1;
        float gxN = (t + 2 < t1) ? Gxr[(size_t)(t + 2 - t0) * 1024 + R] : 0.f;

        float a0 = 0.f, a1 = 0.f, a2 = 0.f, a3 = 0.f;
        if (t > 0) {
            u32* hsc_w = &hsc[w][0];
            #pragma unroll
            for (int q = 0; q < 4; ++q) {              // compile-time q
                const int qq = (b + q) & 3;
                u64* src = &hgx2[(size_t)p * 256 + qq * 64 + l];
                u64 pk;
                for (;;) {
                    pk = __hip_atomic_load(src, __ATOMIC_RELAXED,
                                           __HIP_MEMORY_SCOPE_AGENT);
                    if (__all((u32)(pk >> 32) == (u32)t)) break;
                }
                const float hv = __uint_as_float((u32)pk);
                const float ho = __shfl_xor(hv, 1, 64);
                if (!(l & 1)) hsc_w[l >> 1] = pk2(hv, ho);
                asm volatile("" ::: "memory");   // order: write < reads (TBAA-proof)
                #pragma unroll
                for (int kc = 0; kc < 8; ++kc) {
                    // SAME-TYPE u32 reads (merged to ds_read_b128 by the
                    // compiler WITH correct aliasing vs the u32 write above).
                    const u32 hx = hsc_w[4 * kc + 0];
                    const u32 hy = hsc_w[4 * kc + 1];
                    const u32 hz = hsc_w[4 * kc + 2];
                    const u32 hw2 = hsc_w[4 * kc + 3];
                    a0 = fdot2u(wv2[q * 32 + 4 * kc + 0], hx, a0);
                    a1 = fdot2u(wv2[q * 32 + 4 * kc + 1], hy, a1);
                    a2 = fdot2u(wv2[q * 32 + 4 * kc + 2], hz, a2);
                    a3 = fdot2u(wv2[q * 32 + 4 * kc + 3], hw2, a3);
                }
                asm volatile("" ::: "memory");   // order: reads < next q's write
            }
        }
        const float gv = ((a0 + a1) + (a2 + a3)) + gxA;
        // gate g==2 (cell candidate) uses tanh, others sigmoid
        const float act = (g == 2) ? tanh_fast(gv) : sigm(gv);
        const float a_f = __shfl(act, m + 16, 64);
        const float a_g = __shfl(act, m + 32, 64);
        const float a_o = __shfl(act, m + 48, 64);
        if (l < 16) {                                  // act == sigm(i) here
            const float cn = a_f * c_reg + act * a_g;
            c_reg = cn;
            const float hn = a_o * tanh_fast(cn);
            // publish FIRST (remote critical path)
            const u64 pk = ((u64)(u32)(t + 1) << 32) | (u64)__float_as_uint(hn);
            __hip_atomic_store(&hgx2[(size_t)((t + 1) & 1) * 256 + b * 64 + u],
                               pk, __ATOMIC_RELAXED, __HIP_MEMORY_SCOPE_AGENT);
            hallr[(size_t)(t - t0) * 256 + b * 64 + u] = hn;
        }
        gxA = gxB; gxB = gxN;
    }
    if (l < 16) csave[b * 64 + u] = c_reg;
}

// ---------------------------------------------------------------------------
// Kernel D: logits + log_softmax. One wave per word.
// ---------------------------------------------------------------------------
template <bool BF>
__global__ __launch_bounds__(64) void ktag(
        const u32* __restrict__ dtf,
        int t0, const float* __restrict__ hallr, const void* __restrict__ tagW,
        const void* __restrict__ tagb, void* __restrict__ out) {
    if ((*dtf != 0u) != BF) return;
    const int tr = blockIdx.x, j = threadIdx.x;
    const int t = t0 + tr;
    __shared__ __align__(16) float4 h4[64];
    h4[j] = reinterpret_cast<const float4*>(hallr + (size_t)tr * 256)[j];
    __syncthreads();
    float logit = -1e30f;
    if (j < NTAGS) {
        float a0 = 0.f, a1 = 0.f, a2 = 0.f, a3 = 0.f;
        #pragma unroll
        for (int kc = 0; kc < 64; ++kc) {
            const float4 wvv = ld4<BF>(tagW, (size_t)j * 256 + kc * 4);
            const float4 hv = h4[kc];
            a0 = fmaf(wvv.x, hv.x, a0); a1 = fmaf(wvv.y, hv.y, a1);
            a2 = fmaf(wvv.z, hv.z, a2); a3 = fmaf(wvv.w, hv.w, a3);
        }
        logit = ld1<BF>(tagb, j) + ((a0 + a1) + (a2 + a3));
    }
    float m = logit;
    #pragma unroll
    for (int off = 32; off >= 1; off >>= 1) m = fmaxf(m, __shfl_xor(m, off, 64));
    const float e = (j < NTAGS) ? __expf(logit - m) : 0.f;
    float ssum = e;
    #pragma unroll
    for (int off = 32; off >= 1; off >>= 1) ssum += __shfl_xor(ssum, off, 64);
    if (j < NTAGS)
        st1<BF>(out, (size_t)t * NTAGS + j, logit - m - __logf(ssum));
}

// ---------------------------------------------------------------------------
extern "C" void kernel_launch(void* const* d_in, const int* in_sizes, int n_in,
                              void* d_out, int out_size, void* d_ws, size_t ws_size,
                              hipStream_t stream) {
    const int*  word_idxs = (const int*)d_in[0];
    const int*  char_idxs = (const int*)d_in[1];
    const int*  char_lens = (const int*)d_in[2];
    const void* char_emb  = d_in[3];
    const void* char_Wih  = d_in[4];
    const void* char_Whh  = d_in[5];
    const void* char_bih  = d_in[6];
    const void* char_bhh  = d_in[7];
    const void* word_emb  = d_in[8];
    const void* word_Wih  = d_in[9];
    const void* word_Whh  = d_in[10];
    const void* word_bih  = d_in[11];
    const void* word_bhh  = d_in[12];
    const void* tag_W     = d_in[13];
    const void* tag_b     = d_in[14];

    // ws layout:
    //   [0,64)        dtflag u32
    //   [64,4160)     hgx2 u64[2][256]
    //   [4224,5248)   csave f32[256]
    //   [5248,5504)   xccpub u32[64]
    //   [5504,5508)   gen u32 (persists across launches)
    //   [8192,+2MB)   cfeat f32[8192*64]
    //   [ring0,...)   Gx ring f32[CT*1024] + hall ring f32[CT*256]
    char* ws = (char*)d_ws;
    u32*   dtf    = (u32*)(ws);
    u64*   hgx2   = (u64*)(ws + 64);
    float* csave  = (float*)(ws + 4224);
    u32*   xccpub = (u32*)(ws + 5248);
    u32*   genp   = (u32*)(ws + 5504);
    float* cfeat  = (float*)(ws + 8192);
    const size_t ring0 = 8192 + (size_t)S_LEN * CH * 4;

    int NC = 256;
    const int ncs[9] = {1, 2, 4, 8, 16, 32, 64, 128, 256};
    for (int i = 0; i < 9; ++i) {
        const int ct = S_LEN / ncs[i];
        if (ring0 + (size_t)ct * 5120 <= ws_size) { NC = ncs[i]; break; }
    }
    const int CT = S_LEN / NC;
    float* Gxr   = (float*)(ws + ring0);
    float* hallr = (float*)(ws + ring0 + (size_t)CT * 4096);

    hipLaunchKernelGGL(kdetect, dim3(1), dim3(64), 0, stream, char_emb, dtf, genp);
    hipLaunchKernelGGL(kchar<true>,  dim3(S_LEN / 8), dim3(256), 0, stream,
                       dtf, char_idxs, char_lens, char_emb, char_Wih, char_Whh,
                       char_bih, char_bhh, cfeat);
    hipLaunchKernelGGL(kchar<false>, dim3(S_LEN / 8), dim3(256), 0, stream,
                       dtf, char_idxs, char_lens, char_emb, char_Wih, char_Whh,
                       char_bih, char_bhh, cfeat);
    for (int c = 0; c < NC; ++c) {
        const int t0 = c * CT;
        hipLaunchKernelGGL(kgx<true>,  dim3(CT / 16), dim3(256), 0, stream,
                           dtf, t0, word_idxs, cfeat, word_emb, word_Wih,
                           word_bih, word_bhh, Gxr);
        hipLaunchKernelGGL(kgx<false>, dim3(CT / 16), dim3(256), 0, stream,
                           dtf, t0, word_idxs, cfeat, word_emb, word_Wih,
                           word_bih, word_bhh, Gxr);
        hipLaunchKernelGGL(kwlstm<true>,  dim3(64), dim3(256), 0, stream,
                           dtf, t0, t0 + CT, c, word_Whh, Gxr, hallr, hgx2,
                           csave, xccpub, genp);
        hipLaunchKernelGGL(kwlstm<false>, dim3(64), dim3(256), 0, stream,
                           dtf, t0, t0 + CT, c, word_Whh, Gxr, hallr, hgx2,
                           csave, xccpub, genp);
        hipLaunchKernelGGL(ktag<true>,  dim3(CT), dim3(64), 0, stream,
                           dtf, t0, hallr, tag_W, tag_b, d_out);
        hipLaunchKernelGGL(ktag<false>, dim3(CT), dim3(64), 0, stream,
                           dtf, t0, hallr, tag_W, tag_b, d_out);
    }
}

// Round 6
// 14252.933 us; speedup vs baseline: 2.3128x; 1.0248x over previous
//
#include <hip/hip_runtime.h>
#include <hip/hip_bf16.h>
#include <hip/hip_fp16.h>

#define S_LEN 8192
#define LC 16
#define CE 64
#define CH 64
#define WE 128
#define NTAGS 50

using bf16 = __hip_bfloat16;
typedef unsigned int u32;
typedef unsigned long long u64;

__device__ __forceinline__ float bfbits2f(unsigned short u) {
    union { unsigned int i; float f; } v; v.i = ((unsigned int)u) << 16; return v.f;
}
__device__ __forceinline__ float sigm(float x) {
    return __builtin_amdgcn_rcpf(1.0f + __expf(-x));
}
__device__ __forceinline__ float tanh_fast(float x) {
    return 1.0f - 2.0f * __builtin_amdgcn_rcpf(__expf(2.0f * x) + 1.0f);
}

// dtype-generic accessors ----------------------------------------------------
template <bool BF>
__device__ __forceinline__ float ld1(const void* p, size_t i) {
    if constexpr (BF) return bfbits2f(((const unsigned short*)p)[i]);
    else              return ((const float*)p)[i];
}
template <bool BF>
__device__ __forceinline__ float4 ld4(const void* p, size_t i) {  // elems i..i+3
    if constexpr (BF) {
        const ushort4 s = *reinterpret_cast<const ushort4*>((const unsigned short*)p + i);
        return make_float4(bfbits2f(s.x), bfbits2f(s.y), bfbits2f(s.z), bfbits2f(s.w));
    } else {
        return *reinterpret_cast<const float4*>((const float*)p + i);
    }
}
template <bool BF>
__device__ __forceinline__ void st1(void* p, size_t i, float v) {
    if constexpr (BF) ((bf16*)p)[i] = __float2bfloat16(v);
    else              ((float*)p)[i] = v;
}

// f16-pair helpers for the recurrent matvec (HW-validated R1/R2/R5) ---------
typedef _Float16 h2t __attribute__((ext_vector_type(2)));

__device__ __forceinline__ u32 pk2(float a, float b) {        // RTE pack
    __half2 h = __floats2half2_rn(a, b);
    u32 r; __builtin_memcpy(&r, &h, 4); return r;
}
__device__ __forceinline__ float fdot2u(u32 a, u32 b, float c) {
#if __has_builtin(__builtin_amdgcn_fdot2)
    h2t av, bv;
    __builtin_memcpy(&av, &a, 4);
    __builtin_memcpy(&bv, &b, 4);
    return __builtin_amdgcn_fdot2(av, bv, c, false);
#else
    __half2 ah, bh;
    __builtin_memcpy(&ah, &a, 4);
    __builtin_memcpy(&bh, &b, 4);
    c = fmaf(__half2float(ah.x), __half2float(bh.x), c);
    c = fmaf(__half2float(ah.y), __half2float(bh.y), c);
    return c;
#endif
}

// ---------------------------------------------------------------------------
// Detector: classify float-tensor dtype from char_emb's first 256 ushorts.
// ---------------------------------------------------------------------------
__global__ void kdetect(const void* emb, u32* flag) {
    const int j = threadIdx.x;           // 64 lanes
    int s = 0;
    #pragma unroll
    for (int k = 0; k < 4; ++k) {
        const unsigned short u = ((const unsigned short*)emb)[j * 4 + k];
        const int e = (u >> 7) & 0xFF;
        s += (e >= 100 && e <= 133) ? 1 : 0;
    }
    #pragma unroll
    for (int off = 32; off >= 1; off >>= 1) s += __shfl_xor(s, off, 64);
    if (j == 0) *flag = (s >= 200) ? 1u : 0u;
}

// ---------------------------------------------------------------------------
// Kernel A: char LSTM. 8 words/block, 256 threads (thread j = gate row j).
// ---------------------------------------------------------------------------
template <bool BF>
__global__ __launch_bounds__(256, 2) void kchar(
        const u32* __restrict__ dtf,
        const int* __restrict__ char_idxs, const int* __restrict__ char_lens,
        const void* __restrict__ char_emb,
        const void* __restrict__ Wih, const void* __restrict__ Whh,
        const void* __restrict__ bih, const void* __restrict__ bhh,
        float* __restrict__ cfeat) {
    if ((*dtf != 0u) != BF) return;
    const int j = threadIdx.x;
    const int w0 = blockIdx.x * 8;

    __shared__ __align__(16) float emb_lds[128 * CE];     // 32 KB
    __shared__ __align__(16) float gates_lds[8 * 256];    // 8 KB
    __shared__ __align__(16) float h_lds[8 * CH];
    __shared__ __align__(16) float c_lds[8 * CH];
    __shared__ int cidx_lds[8 * LC];
    __shared__ int len_lds[8];

    {
        float4* emb4 = reinterpret_cast<float4*>(emb_lds);
        #pragma unroll
        for (int i = 0; i < 8; ++i) {
            const int c = i * 256 + j;
            emb4[c] = ld4<BF>(char_emb, (size_t)c * 4);
        }
    }
    if (j < 128) cidx_lds[j] = char_idxs[w0 * LC + j];
    if (j < 8)   len_lds[j]  = char_lens[w0 + j];
    h_lds[j] = 0.f; h_lds[j + 256] = 0.f;
    c_lds[j] = 0.f; c_lds[j + 256] = 0.f;

    float4 wih4[16], whh4[16];
    #pragma unroll
    for (int kc = 0; kc < 16; ++kc) {
        wih4[kc] = ld4<BF>(Wih, (size_t)j * CE + kc * 4);
        whh4[kc] = ld4<BF>(Whh, (size_t)j * CH + kc * 4);
    }
    const float bias = ld1<BF>(bih, j) + ld1<BF>(bhh, j);
    __syncthreads();

    for (int t = 0; t < LC; ++t) {
        for (int w = 0; w < 8; ++w) {
            const int ci = cidx_lds[w * LC + t];
            const float4* x4  = reinterpret_cast<const float4*>(emb_lds + ci * CE);
            const float4* hh4 = reinterpret_cast<const float4*>(h_lds + w * CH);
            float a0 = 0.f, a1 = 0.f, a2 = 0.f, a3 = 0.f;
            #pragma unroll
            for (int kc = 0; kc < 16; ++kc) {
                const float4 xv = x4[kc]; const float4 hv = hh4[kc];
                const float4 wi = wih4[kc]; const float4 wh = whh4[kc];
                a0 = fmaf(wi.x, xv.x, a0); a1 = fmaf(wi.y, xv.y, a1);
                a2 = fmaf(wi.z, xv.z, a2); a3 = fmaf(wi.w, xv.w, a3);
                a0 = fmaf(wh.x, hv.x, a0); a1 = fmaf(wh.y, hv.y, a1);
                a2 = fmaf(wh.z, hv.z, a2); a3 = fmaf(wh.w, hv.w, a3);
            }
            gates_lds[w * 256 + j] = bias + ((a0 + a1) + (a2 + a3));
        }
        __syncthreads();
        #pragma unroll
        for (int rep = 0; rep < 2; ++rep) {
            const int p = j + rep * 256;       // p = w*64 + u
            const int w = p >> 6, u = p & 63;
            const float ig = gates_lds[w * 256 + u];
            const float fg = gates_lds[w * 256 + 64 + u];
            const float gg = gates_lds[w * 256 + 128 + u];
            const float og = gates_lds[w * 256 + 192 + u];
            const float cn = sigm(fg) * c_lds[p] + sigm(ig) * tanh_fast(gg);
            const float hn = sigm(og) * tanh_fast(cn);
            c_lds[p] = cn; h_lds[p] = hn;
            if (t == len_lds[w] - 1)
                cfeat[(size_t)(w0 + w) * CH + u] = hn;
        }
        __syncthreads();
    }
}

// ---------------------------------------------------------------------------
// Kernel B: Gx ring chunk. 16 words/block.
// ---------------------------------------------------------------------------
template <bool BF>
__global__ __launch_bounds__(256) void kgx(
        const u32* __restrict__ dtf,
        int t0, const int* __restrict__ word_idxs, const float* __restrict__ cfeat,
        const void* __restrict__ wemb, const void* __restrict__ Wih,
        const void* __restrict__ bih, const void* __restrict__ bhh,
        float* __restrict__ Gxr) {
    if ((*dtf != 0u) != BF) return;
    const int j = threadIdx.x;
    const int wr0 = blockIdx.x * 16;       // ring row base
    const int w0g = t0 + wr0;              // global word base
    __shared__ __align__(16) float wx[16 * 192];
    __shared__ int widx[16];
    if (j < 16) widx[j] = word_idxs[w0g + j];
    __syncthreads();
    {
        const int w = j >> 4, ch = j & 15;
        const size_t eb = (size_t)widx[w] * WE + ch * 8;
        const float4 f0 = ld4<BF>(wemb, eb), f1 = ld4<BF>(wemb, eb + 4);
        float4* dst = reinterpret_cast<float4*>(wx + w * 192 + ch * 8);
        dst[0] = f0; dst[1] = f1;
        const float4 cf = *reinterpret_cast<const float4*>(
            cfeat + (size_t)(w0g + w) * CH + ch * 4);
        *reinterpret_cast<float4*>(wx + w * 192 + WE + ch * 4) = cf;
    }
    __syncthreads();

    for (int g = 0; g < 4; ++g) {
        const int r = g * 256 + j;
        float acc[16];
        #pragma unroll
        for (int w = 0; w < 16; ++w) acc[w] = 0.f;
        #pragma unroll 8
        for (int kc = 0; kc < 48; ++kc) {
            const float4 wv = ld4<BF>(Wih, (size_t)r * 192 + kc * 4);
            #pragma unroll
            for (int w = 0; w < 16; ++w) {
                const float4 xv = *reinterpret_cast<const float4*>(wx + w * 192 + kc * 4);
                acc[w] = fmaf(wv.x, xv.x, acc[w]);
                acc[w] = fmaf(wv.y, xv.y, acc[w]);
                acc[w] = fmaf(wv.z, xv.z, acc[w]);
                acc[w] = fmaf(wv.w, xv.w, acc[w]);
            }
        }
        const float bias = ld1<BF>(bih, r) + ld1<BF>(bhh, r);
        #pragma unroll
        for (int w = 0; w < 16; ++w)
            Gxr[(size_t)(wr0 + w) * 1024 + r] = acc[w] + bias;
    }
}

// ---------------------------------------------------------------------------
// Kernel C (R6): word LSTM, SINGLE block of 512 threads — the whole 1024x256
// recurrent matvec on one CU. Rationale: R0-R5 established that every
// multi-CU scheme pays an agent-scope publish->observe floor of ~2500-3000cy
// per step (baseline 3150, R2 3160, R5 3940 all converge there). One CU's
// VALU issue for the full matvec is only ~1024cy/SIMD/step -> eliminate the
// comm entirely. No atomics, no protocol: ONE __syncthreads per step.
//
//  * thread j: unit u=j>>1, k=j&1. Rows: k=0 -> {u (gate i), 512+u (g)};
//    k=1 -> {256+u (f), 768+u (o)}. Full rows as f16-pair dwords:
//    cols 0..199 (100 dwords/row) resident in VGPR (200 total);
//    cols 200..255 (28 dwords/row, 7 uint4 quads) in LDS wl[14][512]
//    (114.7KB), lane-contiguous ds_read_b128 -> conflict-free.
//  * h as 128 f16-pair dwords in double-buffered LDS h2[2][128]
//    (broadcast reads). uint4 h reads are safe: __syncthreads between
//    write & read is a memory clobber (R4 TBAA lesson: without a barrier
//    same-type or asm-fence is required).
//  * gates: 2x shfl_xor(1) moves sigm(f),sigm(o) to k=0; k=0 holds c,
//    computes hn; shfl_xor(2) pairs (u,u+1) for the h2 pair-write by
//    j%4==0 lanes.
//  * h/c carried across chunk launches via plain global hsave/csave
//    (stream order guarantees visibility; no tags needed).
// ---------------------------------------------------------------------------
template <bool BF>
__global__ __launch_bounds__(512, 2) void kwlstm(
        const u32* __restrict__ dtf,
        int t0, int t1, const void* __restrict__ whh,
        const float* __restrict__ Gxr,
        float* __restrict__ hallr, u32* __restrict__ hsave,
        float* __restrict__ csave) {
    if ((*dtf != 0u) != BF) return;
    const int j = threadIdx.x;
    const int u = j >> 1;              // unit 0..255
    const int k = j & 1;
    const int rowA = (k ? 256 : 0) + u;    // i or f
    const int rowB = (k ? 768 : 512) + u;  // g or o

    __shared__ __align__(16) uint4 wl[14][512];   // 114.7 KB weight tail
    __shared__ __align__(16) u32 h2[2][128];      // h as f16 pairs, dbuf

    // ---- init: weights ----
    u32 wA[100], wB[100];
    #pragma unroll
    for (int kc = 0; kc < 50; ++kc) {
        const float4 wa = ld4<BF>(whh, (size_t)rowA * 256 + kc * 4);
        wA[2 * kc]     = pk2(wa.x, wa.y);
        wA[2 * kc + 1] = pk2(wa.z, wa.w);
        const float4 wb = ld4<BF>(whh, (size_t)rowB * 256 + kc * 4);
        wB[2 * kc]     = pk2(wb.x, wb.y);
        wB[2 * kc + 1] = pk2(wb.z, wb.w);
    }
    #pragma unroll
    for (int q = 0; q < 7; ++q) {
        const float4 a0 = ld4<BF>(whh, (size_t)rowA * 256 + 200 + q * 8);
        const float4 a1 = ld4<BF>(whh, (size_t)rowA * 256 + 200 + q * 8 + 4);
        wl[q][j] = make_uint4(pk2(a0.x, a0.y), pk2(a0.z, a0.w),
                              pk2(a1.x, a1.y), pk2(a1.z, a1.w));
        const float4 b0 = ld4<BF>(whh, (size_t)rowB * 256 + 200 + q * 8);
        const float4 b1 = ld4<BF>(whh, (size_t)rowB * 256 + 200 + q * 8 + 4);
        wl[7 + q][j] = make_uint4(pk2(b0.x, b0.y), pk2(b0.z, b0.w),
                                  pk2(b1.x, b1.y), pk2(b1.z, b1.w));
    }
    // ---- init: state ----
    if (j < 128) {
        h2[0][j] = 0u; h2[1][j] = 0u;
        if (t0 > 0) h2[t0 & 1][j] = hsave[j];
    }
    float c_reg = 0.f;
    if (k == 0 && t0 > 0) c_reg = csave[u];

    // 2-deep Gx pipeline for both rows
    float gxAA = Gxr[(size_t)0 * 1024 + rowA];
    float gxAB = Gxr[(size_t)0 * 1024 + rowB];
    float gxBA = 0.f, gxBB = 0.f;
    if (t0 + 1 < t1) {
        gxBA = Gxr[(size_t)1 * 1024 + rowA];
        gxBB = Gxr[(size_t)1 * 1024 + rowB];
    }
    __syncthreads();

    for (int t = t0; t < t1; ++t) {
        const int p = t & 1;
        float gxNA = 0.f, gxNB = 0.f;              // prefetch Gx[t+2]
        if (t + 2 < t1) {
            gxNA = Gxr[(size_t)(t + 2 - t0) * 1024 + rowA];
            gxNB = Gxr[(size_t)(t + 2 - t0) * 1024 + rowB];
        }

        float aA0 = 0.f, aA1 = 0.f, aB0 = 0.f, aB1 = 0.f;
        if (t > 0) {
            const uint4* h4 = reinterpret_cast<const uint4*>(&h2[p][0]);
            #pragma unroll
            for (int q = 0; q < 25; ++q) {         // h dwords 0..99 (VGPR w)
                const uint4 hv = h4[q];            // broadcast read
                aA0 = fdot2u(wA[4 * q + 0], hv.x, aA0);
                aA1 = fdot2u(wA[4 * q + 1], hv.y, aA1);
                aA0 = fdot2u(wA[4 * q + 2], hv.z, aA0);
                aA1 = fdot2u(wA[4 * q + 3], hv.w, aA1);
                aB0 = fdot2u(wB[4 * q + 0], hv.x, aB0);
                aB1 = fdot2u(wB[4 * q + 1], hv.y, aB1);
                aB0 = fdot2u(wB[4 * q + 2], hv.z, aB0);
                aB1 = fdot2u(wB[4 * q + 3], hv.w, aB1);
            }
            #pragma unroll
            for (int q = 0; q < 7; ++q) {          // h dwords 100..127 (LDS w)
                const uint4 hv = h4[25 + q];
                const uint4 wa = wl[q][j];
                const uint4 wb = wl[7 + q][j];
                aA0 = fdot2u(wa.x, hv.x, aA0);
                aA1 = fdot2u(wa.y, hv.y, aA1);
                aA0 = fdot2u(wa.z, hv.z, aA0);
                aA1 = fdot2u(wa.w, hv.w, aA1);
                aB0 = fdot2u(wb.x, hv.x, aB0);
                aB1 = fdot2u(wb.y, hv.y, aB1);
                aB0 = fdot2u(wb.z, hv.z, aB0);
                aB1 = fdot2u(wb.w, hv.w, aB1);
            }
        }
        const float gA = (aA0 + aA1) + gxAA;       // rowA gate value
        const float gB = (aB0 + aB1) + gxAB;       // rowB gate value
        // k=0: rowA=i (sigm), rowB=g (tanh); k=1: rowA=f (sigm), rowB=o (sigm)
        const float actA = sigm(gA);
        const float actB = k ? sigm(gB) : tanh_fast(gB);
        const float xfA = __shfl_xor(actA, 1, 64); // k=0 <- sigm(f)
        const float xfB = __shfl_xor(actB, 1, 64); // k=0 <- sigm(o)
        float hn = 0.f;
        if (k == 0) {
            const float cn = xfA * c_reg + actA * actB;
            c_reg = cn;
            hn = xfB * tanh_fast(cn);
            hallr[(size_t)(t - t0) * 256 + u] = hn;
        }
        const float ho = __shfl_xor(hn, 2, 64);    // j=4m <- hn(u+1)
        if ((j & 3) == 0) h2[p ^ 1][u >> 1] = pk2(hn, ho);
        __syncthreads();                           // h2[p^1] ready for t+1
        gxAA = gxBA; gxAB = gxBB; gxBA = gxNA; gxBB = gxNB;
    }
    // ---- save state for next chunk ----
    if (j < 128) hsave[j] = h2[t1 & 1][j];
    if (k == 0)  csave[u] = c_reg;
}

// ---------------------------------------------------------------------------
// Kernel D: logits + log_softmax. One wave per word.
// ---------------------------------------------------------------------------
template <bool BF>
__global__ __launch_bounds__(64) void ktag(
        const u32* __restrict__ dtf,
        int t0, const float* __restrict__ hallr, const void* __restrict__ tagW,
        const void* __restrict__ tagb, void* __restrict__ out) {
    if ((*dtf != 0u) != BF) return;
    const int tr = blockIdx.x, j = threadIdx.x;
    const int t = t0 + tr;
    __shared__ __align__(16) float4 h4[64];
    h4[j] = reinterpret_cast<const float4*>(hallr + (size_t)tr * 256)[j];
    __syncthreads();
    float logit = -1e30f;
    if (j < NTAGS) {
        float a0 = 0.f, a1 = 0.f, a2 = 0.f, a3 = 0.f;
        #pragma unroll
        for (int kc = 0; kc < 64; ++kc) {
            const float4 wvv = ld4<BF>(tagW, (size_t)j * 256 + kc * 4);
            const float4 hv = h4[kc];
            a0 = fmaf(wvv.x, hv.x, a0); a1 = fmaf(wvv.y, hv.y, a1);
            a2 = fmaf(wvv.z, hv.z, a2); a3 = fmaf(wvv.w, hv.w, a3);
        }
        logit = ld1<BF>(tagb, j) + ((a0 + a1) + (a2 + a3));
    }
    float m = logit;
    #pragma unroll
    for (int off = 32; off >= 1; off >>= 1) m = fmaxf(m, __shfl_xor(m, off, 64));
    const float e = (j < NTAGS) ? __expf(logit - m) : 0.f;
    float ssum = e;
    #pragma unroll
    for (int off = 32; off >= 1; off >>= 1) ssum += __shfl_xor(ssum, off, 64);
    if (j < NTAGS)
        st1<BF>(out, (size_t)t * NTAGS + j, logit - m - __logf(ssum));
}

// ---------------------------------------------------------------------------
extern "C" void kernel_launch(void* const* d_in, const int* in_sizes, int n_in,
                              void* d_out, int out_size, void* d_ws, size_t ws_size,
                              hipStream_t stream) {
    const int*  word_idxs = (const int*)d_in[0];
    const int*  char_idxs = (const int*)d_in[1];
    const int*  char_lens = (const int*)d_in[2];
    const void* char_emb  = d_in[3];
    const void* char_Wih  = d_in[4];
    const void* char_Whh  = d_in[5];
    const void* char_bih  = d_in[6];
    const void* char_bhh  = d_in[7];
    const void* word_emb  = d_in[8];
    const void* word_Wih  = d_in[9];
    const void* word_Whh  = d_in[10];
    const void* word_bih  = d_in[11];
    const void* word_bhh  = d_in[12];
    const void* tag_W     = d_in[13];
    const void* tag_b     = d_in[14];

    // ws layout:
    //   [0,64)        dtflag u32
    //   [64,576)      hsave u32[128] (f16-pair h carry across chunks)
    //   [4224,5248)   csave f32[256]
    //   [8192,+2MB)   cfeat f32[8192*64]
    //   [ring0,...)   Gx ring f32[CT*1024] + hall ring f32[CT*256]
    char* ws = (char*)d_ws;
    u32*   dtf    = (u32*)(ws);
    u32*   hsave  = (u32*)(ws + 64);
    float* csave  = (float*)(ws + 4224);
    float* cfeat  = (float*)(ws + 8192);
    const size_t ring0 = 8192 + (size_t)S_LEN * CH * 4;

    int NC = 256;
    const int ncs[9] = {1, 2, 4, 8, 16, 32, 64, 128, 256};
    for (int i = 0; i < 9; ++i) {
        const int ct = S_LEN / ncs[i];
        if (ring0 + (size_t)ct * 5120 <= ws_size) { NC = ncs[i]; break; }
    }
    const int CT = S_LEN / NC;
    float* Gxr   = (float*)(ws + ring0);
    float* hallr = (float*)(ws + ring0 + (size_t)CT * 4096);

    hipLaunchKernelGGL(kdetect, dim3(1), dim3(64), 0, stream, char_emb, dtf);
    hipLaunchKernelGGL(kchar<true>,  dim3(S_LEN / 8), dim3(256), 0, stream,
                       dtf, char_idxs, char_lens, char_emb, char_Wih, char_Whh,
                       char_bih, char_bhh, cfeat);
    hipLaunchKernelGGL(kchar<false>, dim3(S_LEN / 8), dim3(256), 0, stream,
                       dtf, char_idxs, char_lens, char_emb, char_Wih, char_Whh,
                       char_bih, char_bhh, cfeat);
    for (int c = 0; c < NC; ++c) {
        const int t0 = c * CT;
        hipLaunchKernelGGL(kgx<true>,  dim3(CT / 16), dim3(256), 0, stream,
                           dtf, t0, word_idxs, cfeat, word_emb, word_Wih,
                           word_bih, word_bhh, Gxr);
        hipLaunchKernelGGL(kgx<false>, dim3(CT / 16), dim3(256), 0, stream,
                           dtf, t0, word_idxs, cfeat, word_emb, word_Wih,
                           word_bih, word_bhh, Gxr);
        hipLaunchKernelGGL(kwlstm<true>,  dim3(1), dim3(512), 0, stream,
                           dtf, t0, t0 + CT, word_Whh, Gxr, hallr, hsave, csave);
        hipLaunchKernelGGL(kwlstm<false>, dim3(1), dim3(512), 0, stream,
                           dtf, t0, t0 + CT, word_Whh, Gxr, hallr, hsave, csave);
        hipLaunchKernelGGL(ktag<true>,  dim3(CT), dim3(64), 0, stream,
                           dtf, t0, hallr, tag_W, tag_b, d_out);
        hipLaunchKernelGGL(ktag<false>, dim3(CT), dim3(64), 0, stream,
                           dtf, t0, hallr, tag_W, tag_b, d_out);
    }
}